// Round 4
// baseline (2440.583 us; speedup 1.0000x reference)
//
#include <hip/hip_runtime.h>

// LSTM S=512 B=64 I=256 H=512, gates order f,i,o,g (4H=2048 cols).
// Persistent-register weights, fused [x_t|h] @ W recurrent GEMM.
// R6: data-embedded sync. Each exchanged h element is a 32-bit word:
// (tag=t+1)<<16 | bf16(h). Consumers poll the data itself (agent-scope u64
// loads), check all hi-16 tags == t, unpack lo-16 into MFMA fragments.
// Deletes: flag words, the producer vmcnt(0) drain, and the separate h-load
// round trip -- one IF store-propagation + one combined poll/load instead of
// three serialized traversals. Per-word tags are torn-visibility-safe (4B
// stores are atomic); exact-match tags + double buffer are deadlock-free
// (all-to-all dependency bounds inter-block skew to 1 step, so a buffer is
// overwritten only two steps after its last reader). No inline asm anywhere.
// Wave0 runs its 32 h-independent x-MFMAs before polling.

#define S_LEN 512
#define NBLK  128

typedef __attribute__((ext_vector_type(8))) __bf16 bf16x8;
typedef __attribute__((ext_vector_type(4))) float  f32x4;

// workspace layout (bytes)
#define OFF_W    ((size_t)0)          // swizzled W: 3,145,728
#define OFF_BIAS ((size_t)3145728)    // 2048 f32
#define OFF_X    ((size_t)4194304)    // x bf16: 16,777,216
#define OFF_H    ((size_t)20971520)   // tagged h double buffer: 2*64*512*4 = 262144

// ---- prelude: x fp32 -> bf16 ----
__global__ void k_conv_x(const float* __restrict__ x, __bf16* __restrict__ xb) {
  int i = blockIdx.x * 256 + threadIdx.x;      // 2,097,152 threads exactly
  float4 v = ((const float4*)x)[i];
  union { __bf16 b[4]; uint2 u; } p;
  p.b[0] = (__bf16)v.x; p.b[1] = (__bf16)v.y;
  p.b[2] = (__bf16)v.z; p.b[3] = (__bf16)v.w;
  ((uint2*)xb)[i] = p.u;
}

// ---- prelude: W -> bf16, MFMA-B-fragment-swizzled ----
// frag tid = ((hs*4+g)*24 + kk)*64 + L ; lane L holds 8 bf16:
// W[k = kk*32 + (L>>4)*8 + j][col = hs*16 + (L&15)] ; k<256 -> Wx else Wh.
__global__ void k_conv_w(const float* __restrict__ wxf, const float* __restrict__ whf,
                         const float* __restrict__ wxi, const float* __restrict__ whi,
                         const float* __restrict__ wxo, const float* __restrict__ who,
                         const float* __restrict__ wxg, const float* __restrict__ whg,
                         __bf16* __restrict__ Wswz) {
  int tid = blockIdx.x * 256 + threadIdx.x;    // 196,608 threads exactly
  int L = tid & 63;
  int q = tid >> 6;
  int kk = q % 24;
  int q2 = q / 24;
  int g  = q2 & 3;
  int hs = q2 >> 2;
  const float* Wx = (g == 0) ? wxf : (g == 1) ? wxi : (g == 2) ? wxo : wxg;
  const float* Wh = (g == 0) ? whf : (g == 1) ? whi : (g == 2) ? who : whg;
  int col = hs * 16 + (L & 15);
  int k0  = kk * 32 + (L >> 4) * 8;
  union { __bf16 b[8]; uint4 u; } p;
#pragma unroll
  for (int j = 0; j < 8; ++j) {
    int k = k0 + j;
    float v = (k < 256) ? Wx[k * 512 + col] : Wh[(k - 256) * 512 + col];
    p.b[j] = (__bf16)v;
  }
  ((uint4*)Wswz)[tid] = p.u;
}

// ---- prelude: combined bias b = bx + bh, layout [gate][512] ----
__global__ void k_conv_bias(const float* __restrict__ bxf, const float* __restrict__ bhf,
                            const float* __restrict__ bxi, const float* __restrict__ bhi,
                            const float* __restrict__ bxo, const float* __restrict__ bho,
                            const float* __restrict__ bxg, const float* __restrict__ bhg,
                            float* __restrict__ bc) {
  int n = blockIdx.x * 256 + threadIdx.x;      // 2048 exactly
  int g = n >> 9, h = n & 511;
  const float* bx = (g == 0) ? bxf : (g == 1) ? bxi : (g == 2) ? bxo : bxg;
  const float* bh = (g == 0) ? bhf : (g == 1) ? bhi : (g == 2) ? bho : bhg;
  bc[n] = bx[h] + bh[h];
}

__device__ __forceinline__ float sigm(float x) { return 1.f / (1.f + __expf(-x)); }
__device__ __forceinline__ float tanh_f(float x) { return 1.f - 2.f / (1.f + __expf(2.f * x)); }

// ---- main recurrent kernel ----
// block (mt, hs): mt = batch tile (16 rows), hs = hidden slice (16 units).
// wave0: K=[0,384) (x + h[0:128)); wave1: K=[384,768) (h[128:512)).
// Partial sums reduced through LDS; wave1 does gates/c/h + output stores.
// h exchange: tagged u32 words, double-buffered by step parity.
//   producer at end of step t: word = (t+1)<<16 | bf16bits  -> buffer (t+1)&1
//   consumer at step t: polls its fragments in buffer t&1 until all tags == t
// (t=0 passes instantly on the zeroed buffer: tag 0 == expected 0, data 0.)
__global__ __launch_bounds__(128, 1) void lstm_seq(
    const __bf16* __restrict__ Wswz, const float* __restrict__ bias,
    const __bf16* __restrict__ xb, unsigned int* __restrict__ hw,
    float* __restrict__ out) {
  const int tid  = threadIdx.x;
  const int w    = tid >> 6;
  const int L    = tid & 63;
  const int quad = L >> 4;
  const int lc   = L & 15;
  const int mt   = blockIdx.x & 3;
  const int hs   = blockIdx.x >> 2;

  __shared__ f32x4 red[4][64];

  // persistent weight fragments: 12 K-steps x 4 gates
  bf16x8 Wf[12][4];
  {
    const uint4* wp = (const uint4*)Wswz;
#pragma unroll
    for (int g = 0; g < 4; ++g)
#pragma unroll
      for (int kkl = 0; kkl < 12; ++kkl) {
        int kk = w * 12 + kkl;
        uint4 u = wp[(((size_t)(hs * 4 + g) * 24 + kk) << 6) + L];
        Wf[kkl][g] = __builtin_bit_cast(bf16x8, u);
      }
  }
  float bsv[4];
#pragma unroll
  for (int g = 0; g < 4; ++g) bsv[g] = bias[g * 512 + hs * 16 + lc];

  const int row = mt * 16 + lc;              // A-row this lane loads
  const __bf16* px = xb + (size_t)row * 256 + quad * 8;
  // tagged-h read base for this lane (word units)
  const unsigned int* ph0 = hw + (size_t)row * 512 + quad * 8;
  const unsigned int* ph1 = ph0 + 32768;

  f32x4 cst = {0.f, 0.f, 0.f, 0.f};          // cell state (wave1 only)

  for (int t = 0; t < S_LEN; ++t) {
    const unsigned int* rdw = (t & 1) ? ph1 : ph0;
    const unsigned int tagv = (unsigned int)t;
    const unsigned long long tagpat =
        ((unsigned long long)tagv << 16) | ((unsigned long long)tagv << 48);
    const unsigned long long tagmask = 0xFFFF0000FFFF0000ull;

    f32x4 acc[4] = {{0,0,0,0},{0,0,0,0},{0,0,0,0},{0,0,0,0}};

    if (w == 0) {
      // ---- x part first: no h dependency, runs before/while h propagates ----
      bf16x8 Ax[8];
#pragma unroll
      for (int kkl = 0; kkl < 8; ++kkl)
        Ax[kkl] = __builtin_bit_cast(bf16x8, *(const uint4*)(px + kkl * 32));
#pragma unroll
      for (int kkl = 0; kkl < 8; ++kkl)
#pragma unroll
        for (int g = 0; g < 4; ++g)
          acc[g] = __builtin_amdgcn_mfma_f32_16x16x32_bf16(Ax[kkl], Wf[kkl][g], acc[g], 0, 0, 0);

      // ---- poll h[0:128): 4 fragments = 16 tagged u64 ----
      unsigned long long q[16];
      for (;;) {
#pragma unroll
        for (int f = 0; f < 4; ++f)
#pragma unroll
          for (int j = 0; j < 4; ++j)
            q[f * 4 + j] = __hip_atomic_load(
                (const unsigned long long*)(rdw + f * 32) + j,
                __ATOMIC_RELAXED, __HIP_MEMORY_SCOPE_AGENT);
        unsigned long long st = 0;
#pragma unroll
        for (int i = 0; i < 16; ++i) st |= (q[i] ^ tagpat) & tagmask;
        if (__ballot(st != 0ull) == 0ull) break;
      }
      // unpack lo16s -> bf16x8 fragments, MFMA h part
#pragma unroll
      for (int f = 0; f < 4; ++f) {
        uint4 d;
        unsigned long long v0 = q[f * 4 + 0], v1 = q[f * 4 + 1];
        unsigned long long v2 = q[f * 4 + 2], v3 = q[f * 4 + 3];
        d.x = (unsigned int)(v0 & 0xFFFFu) | (unsigned int)((v0 >> 16) & 0xFFFF0000u);
        d.y = (unsigned int)(v1 & 0xFFFFu) | (unsigned int)((v1 >> 16) & 0xFFFF0000u);
        d.z = (unsigned int)(v2 & 0xFFFFu) | (unsigned int)((v2 >> 16) & 0xFFFF0000u);
        d.w = (unsigned int)(v3 & 0xFFFFu) | (unsigned int)((v3 >> 16) & 0xFFFF0000u);
        bf16x8 Ah = __builtin_bit_cast(bf16x8, d);
#pragma unroll
        for (int g = 0; g < 4; ++g)
          acc[g] = __builtin_amdgcn_mfma_f32_16x16x32_bf16(Ah, Wf[8 + f][g], acc[g], 0, 0, 0);
      }

#pragma unroll
      for (int g = 0; g < 4; ++g) red[g][L] = acc[g];
    } else {
      // ---- wave1: poll h[128:512): 12 fragments = 48 tagged u64 ----
      unsigned long long q[48];
      for (;;) {
#pragma unroll
        for (int f = 0; f < 12; ++f)
#pragma unroll
          for (int j = 0; j < 4; ++j)
            q[f * 4 + j] = __hip_atomic_load(
                (const unsigned long long*)(rdw + 128 + f * 32) + j,
                __ATOMIC_RELAXED, __HIP_MEMORY_SCOPE_AGENT);
        unsigned long long st = 0;
#pragma unroll
        for (int i = 0; i < 48; ++i) st |= (q[i] ^ tagpat) & tagmask;
        if (__ballot(st != 0ull) == 0ull) break;
      }
#pragma unroll
      for (int f = 0; f < 12; ++f) {
        uint4 d;
        unsigned long long v0 = q[f * 4 + 0], v1 = q[f * 4 + 1];
        unsigned long long v2 = q[f * 4 + 2], v3 = q[f * 4 + 3];
        d.x = (unsigned int)(v0 & 0xFFFFu) | (unsigned int)((v0 >> 16) & 0xFFFF0000u);
        d.y = (unsigned int)(v1 & 0xFFFFu) | (unsigned int)((v1 >> 16) & 0xFFFF0000u);
        d.z = (unsigned int)(v2 & 0xFFFFu) | (unsigned int)((v2 >> 16) & 0xFFFF0000u);
        d.w = (unsigned int)(v3 & 0xFFFFu) | (unsigned int)((v3 >> 16) & 0xFFFF0000u);
        bf16x8 Ah = __builtin_bit_cast(bf16x8, d);
#pragma unroll
        for (int g = 0; g < 4; ++g)
          acc[g] = __builtin_amdgcn_mfma_f32_16x16x32_bf16(Ah, Wf[f][g], acc[g], 0, 0, 0);
      }
    }

    __syncthreads();

    if (w == 1) {
      unsigned int* wrw = hw + (((t + 1) & 1) ? 32768 : 0);
#pragma unroll
      for (int g = 0; g < 4; ++g) acc[g] += red[g][L];
      const int col = hs * 16 + lc;

      // compute all 4 rows (keep hv/cn in regs)
      float hv_[4], cn_[4];
#pragma unroll
      for (int r = 0; r < 4; ++r) {
        float fg = sigm(acc[0][r] + bsv[0]);
        float ig = sigm(acc[1][r] + bsv[1]);
        float og = sigm(acc[2][r] + bsv[2]);
        float gg = tanh_f(acc[3][r] + bsv[3]);
        float cn = fg * cst[r] + ig * gg;
        cst[r] = cn;
        cn_[r] = cn;
        hv_[r] = og * tanh_f(cn);
      }

      // tagged h stores: tag = t+1 packed with the data -- no drain, no flag.
#pragma unroll
      for (int r = 0; r < 4; ++r) {
        int orow = mt * 16 + quad * 4 + r;
        unsigned int hbits =
            (unsigned int)__builtin_bit_cast(unsigned short, (__bf16)hv_[r]);
        unsigned int word = ((unsigned int)(t + 1) << 16) | hbits;
        __hip_atomic_store(&wrw[orow * 512 + col], word,
                           __ATOMIC_RELAXED, __HIP_MEMORY_SCOPE_AGENT);
      }
      // HBM output stores after the h publish -- off the critical path
      float* oseq = out + (size_t)t * 64 * 512;
#pragma unroll
      for (int r = 0; r < 4; ++r) {
        int orow = mt * 16 + quad * 4 + r;
        oseq[orow * 512 + col] = hv_[r];
        if (t == S_LEN - 1) {
          out[16777216 + orow * 512 + col] = hv_[r];               // final h
          out[16777216 + 32768 + orow * 512 + col] = cn_[r];       // final c
        }
      }
    }
    px += 64 * 256;
  }
}

extern "C" void kernel_launch(void* const* d_in, const int* in_sizes, int n_in,
                              void* d_out, int out_size, void* d_ws, size_t ws_size,
                              hipStream_t stream) {
  char* ws = (char*)d_ws;
  __bf16* Wswz = (__bf16*)(ws + OFF_W);
  float*  bias = (float*)(ws + OFF_BIAS);
  __bf16* xb   = (__bf16*)(ws + OFF_X);
  unsigned int* hw = (unsigned int*)(ws + OFF_H);

  // zero tagged-h double buffer (ws is poisoned 0xAA each call);
  // zero tags make the t=0 poll pass instantly with h=0.
  hipMemsetAsync(ws + OFF_H, 0, 262144, stream);

  k_conv_x<<<8192, 256, 0, stream>>>((const float*)d_in[0], xb);
  k_conv_w<<<768, 256, 0, stream>>>(
      (const float*)d_in[1],  (const float*)d_in[3],    // f: Wx, Wh
      (const float*)d_in[5],  (const float*)d_in[7],    // i
      (const float*)d_in[9],  (const float*)d_in[11],   // o
      (const float*)d_in[13], (const float*)d_in[15],   // g
      Wswz);
  k_conv_bias<<<8, 256, 0, stream>>>(
      (const float*)d_in[2],  (const float*)d_in[4],
      (const float*)d_in[6],  (const float*)d_in[8],
      (const float*)d_in[10], (const float*)d_in[12],
      (const float*)d_in[14], (const float*)d_in[16],
      bias);
  lstm_seq<<<NBLK, 128, 0, stream>>>(Wswz, bias, xb, hw, (float*)d_out);
}

// Round 7
// 2075.398 us; speedup vs baseline: 1.1760x; 1.1760x over previous
//
#include <hip/hip_runtime.h>

// LSTM S=512 B=64 I=256 H=512, gates order f,i,o,g (4H=2048 cols).
// Persistent-register weights, fused [x_t|h] @ W recurrent GEMM.
// R9 = R3 skeleton (proven 1711us; 64B-strided per-producer flags) + two
// low-risk deltas:
//  (1) poll backoff: immediate first check, then s_sleep(1) (~64cy) between
//      retries; only dependency lanes issue the flag load (wave0: 8 lines,
//      wave1: 24). Cuts spin transaction rate ~10-20x to test the theory
//      that poll-storm congestion at the IF inflates the producers' h-store
//      drain and the consumers' detect latency.
//  (2) wave0 issues its 32 h-independent x-MFMAs BEFORE the flag wait
//      (register-only reorder, accumulation order preserved).
// R7/R8 lesson (container died twice = likely GPU hang): do NOT pack many
// cross-XCD flag writers into one cache line under continuous poll load;
// per-writer 64B lines + lower poll rate instead.

#define S_LEN 512
#define NBLK  128
#define GROUP 32

typedef __attribute__((ext_vector_type(8))) __bf16 bf16x8;
typedef __attribute__((ext_vector_type(4))) float  f32x4;

// workspace layout (bytes)
#define OFF_W    ((size_t)0)          // swizzled W: 3,145,728
#define OFF_BIAS ((size_t)3145728)    // 2048 f32
#define OFF_X    ((size_t)4194304)    // x bf16: 16,777,216
#define OFF_H    ((size_t)20971520)   // h double buffer: 2*64*512*2 = 131072
#define OFF_FLG  ((size_t)21102592)   // 4 groups * 32 producers * 64B = 8192

// ---- prelude: x fp32 -> bf16 ----
__global__ void k_conv_x(const float* __restrict__ x, __bf16* __restrict__ xb) {
  int i = blockIdx.x * 256 + threadIdx.x;      // 2,097,152 threads exactly
  float4 v = ((const float4*)x)[i];
  union { __bf16 b[4]; uint2 u; } p;
  p.b[0] = (__bf16)v.x; p.b[1] = (__bf16)v.y;
  p.b[2] = (__bf16)v.z; p.b[3] = (__bf16)v.w;
  ((uint2*)xb)[i] = p.u;
}

// ---- prelude: W -> bf16, MFMA-B-fragment-swizzled ----
// frag tid = ((hs*4+g)*24 + kk)*64 + L ; lane L holds 8 bf16:
// W[k = kk*32 + (L>>4)*8 + j][col = hs*16 + (L&15)] ; k<256 -> Wx else Wh.
__global__ void k_conv_w(const float* __restrict__ wxf, const float* __restrict__ whf,
                         const float* __restrict__ wxi, const float* __restrict__ whi,
                         const float* __restrict__ wxo, const float* __restrict__ who,
                         const float* __restrict__ wxg, const float* __restrict__ whg,
                         __bf16* __restrict__ Wswz) {
  int tid = blockIdx.x * 256 + threadIdx.x;    // 196,608 threads exactly
  int L = tid & 63;
  int q = tid >> 6;
  int kk = q % 24;
  int q2 = q / 24;
  int g  = q2 & 3;
  int hs = q2 >> 2;
  const float* Wx = (g == 0) ? wxf : (g == 1) ? wxi : (g == 2) ? wxo : wxg;
  const float* Wh = (g == 0) ? whf : (g == 1) ? whi : (g == 2) ? who : whg;
  int col = hs * 16 + (L & 15);
  int k0  = kk * 32 + (L >> 4) * 8;
  union { __bf16 b[8]; uint4 u; } p;
#pragma unroll
  for (int j = 0; j < 8; ++j) {
    int k = k0 + j;
    float v = (k < 256) ? Wx[k * 512 + col] : Wh[(k - 256) * 512 + col];
    p.b[j] = (__bf16)v;
  }
  ((uint4*)Wswz)[tid] = p.u;
}

// ---- prelude: combined bias b = bx + bh, layout [gate][512] ----
__global__ void k_conv_bias(const float* __restrict__ bxf, const float* __restrict__ bhf,
                            const float* __restrict__ bxi, const float* __restrict__ bhi,
                            const float* __restrict__ bxo, const float* __restrict__ bho,
                            const float* __restrict__ bxg, const float* __restrict__ bhg,
                            float* __restrict__ bc) {
  int n = blockIdx.x * 256 + threadIdx.x;      // 2048 exactly
  int g = n >> 9, h = n & 511;
  const float* bx = (g == 0) ? bxf : (g == 1) ? bxi : (g == 2) ? bxo : bxg;
  const float* bh = (g == 0) ? bhf : (g == 1) ? bhi : (g == 2) ? bho : bhg;
  bc[n] = bx[h] + bh[h];
}

__device__ __forceinline__ float sigm(float x) { return 1.f / (1.f + __expf(-x)); }
__device__ __forceinline__ float tanh_f(float x) { return 1.f - 2.f / (1.f + __expf(2.f * x)); }

// device-scope (IF-coherent, L2-bypass) 16B h-fragment load as 2x b64 atomics
__device__ __forceinline__ bf16x8 load_h8(const __bf16* p) {
  union { unsigned long long q[2]; bf16x8 v; } u;
  u.q[0] = __hip_atomic_load((const unsigned long long*)p,       __ATOMIC_RELAXED, __HIP_MEMORY_SCOPE_AGENT);
  u.q[1] = __hip_atomic_load((const unsigned long long*)(p + 4), __ATOMIC_RELAXED, __HIP_MEMORY_SCOPE_AGENT);
  return u.v;
}

// ---- main recurrent kernel ----
// block (mt, hs): mt = batch tile (16 rows), hs = hidden slice (16 units).
// wave0: K=[0,384) (x + h[0:128)); wave1: K=[384,768) (h[128:512)).
// Partial sums reduced through LDS; wave1 does gates/c/h + output stores.
// Arrival: per-producer flag word (64B lines), value = last completed step+1.
// Poll: dependency lanes only, immediate first check, s_sleep(1) backoff.
__global__ __launch_bounds__(128, 1) void lstm_seq(
    const __bf16* __restrict__ Wswz, const float* __restrict__ bias,
    const __bf16* __restrict__ xb, __bf16* __restrict__ hb,
    unsigned int* __restrict__ flg, float* __restrict__ out) {
  const int tid  = threadIdx.x;
  const int w    = tid >> 6;
  const int L    = tid & 63;
  const int quad = L >> 4;
  const int lc   = L & 15;
  const int mt   = blockIdx.x & 3;
  const int hs   = blockIdx.x >> 2;

  __shared__ f32x4 red[4][64];

  // persistent weight fragments: 12 K-steps x 4 gates
  bf16x8 Wf[12][4];
  {
    const uint4* wp = (const uint4*)Wswz;
#pragma unroll
    for (int g = 0; g < 4; ++g)
#pragma unroll
      for (int kkl = 0; kkl < 12; ++kkl) {
        int kk = w * 12 + kkl;
        uint4 u = wp[(((size_t)(hs * 4 + g) * 24 + kk) << 6) + L];
        Wf[kkl][g] = __builtin_bit_cast(bf16x8, u);
      }
  }
  float bsv[4];
#pragma unroll
  for (int g = 0; g < 4; ++g) bsv[g] = bias[g * 512 + hs * 16 + lc];

  const int row = mt * 16 + lc;              // A-row this lane loads
  const __bf16* px = xb + (size_t)row * 256 + quad * 8;
  const __bf16* ph0 = hb + (size_t)row * 512 + quad * 8;
  const __bf16* ph1 = ph0 + 32768;

  // poll setup: lane q = L&31 watches flag of producer (mt, q), 64B stride
  const int q = L & 31;
  const unsigned int* fpoll = flg + (((size_t)mt * 32 + q) << 4);
  const bool fdep = (w == 0) ? (q < 8) : (q >= 8);
  unsigned int* fmine = flg + (((size_t)mt * 32 + hs) << 4);

  f32x4 cst = {0.f, 0.f, 0.f, 0.f};          // cell state (wave1 only)

  for (int t = 0; t < S_LEN; ++t) {
    const __bf16* rd = (t & 1) ? ph1 : ph0;
    bf16x8 Af[12];
    f32x4 acc[4] = {{0,0,0,0},{0,0,0,0},{0,0,0,0},{0,0,0,0}};

    // wave0: x loads + x-MFMAs BEFORE the wait (no h dependency; accumulation
    // order identical to R3's kkl=0..11 loop, so numerics are unchanged)
    if (w == 0) {
#pragma unroll
      for (int kkl = 0; kkl < 8; ++kkl)
        Af[kkl] = __builtin_bit_cast(bf16x8, *(const uint4*)(px + kkl * 32));
#pragma unroll
      for (int kkl = 0; kkl < 8; ++kkl)
#pragma unroll
        for (int g = 0; g < 4; ++g)
          acc[g] = __builtin_amdgcn_mfma_f32_16x16x32_bf16(Af[kkl], Wf[kkl][g], acc[g], 0, 0, 0);
    }

    // wait for previous step's producers this wave depends on:
    // dependency lanes only; immediate first check; s_sleep backoff
    if (t > 0) {
      const unsigned int need = (unsigned int)t;
      for (;;) {
        unsigned int f = 0;
        if (fdep)
          f = __hip_atomic_load(fpoll, __ATOMIC_RELAXED,
                                __HIP_MEMORY_SCOPE_AGENT);
        if (__ballot(fdep && (f < need)) == 0ull) break;
        __builtin_amdgcn_s_sleep(1);
      }
    }

    // h fragment loads, device-scope (bypass stale L2, hit IF)
    if (w == 0) {
#pragma unroll
      for (int kkl = 8; kkl < 12; ++kkl)
        Af[kkl] = load_h8(rd + (kkl - 8) * 32);
#pragma unroll
      for (int kkl = 8; kkl < 12; ++kkl)
#pragma unroll
        for (int g = 0; g < 4; ++g)
          acc[g] = __builtin_amdgcn_mfma_f32_16x16x32_bf16(Af[kkl], Wf[kkl][g], acc[g], 0, 0, 0);
    } else {
#pragma unroll
      for (int kkl = 0; kkl < 12; ++kkl)
        Af[kkl] = load_h8(rd + 128 + kkl * 32);
#pragma unroll
      for (int kkl = 0; kkl < 12; ++kkl)
#pragma unroll
        for (int g = 0; g < 4; ++g)
          acc[g] = __builtin_amdgcn_mfma_f32_16x16x32_bf16(Af[kkl], Wf[kkl][g], acc[g], 0, 0, 0);
    }

    if (w == 0) {
#pragma unroll
      for (int g = 0; g < 4; ++g) red[g][L] = acc[g];
    }
    __syncthreads();

    if (w == 1) {
      __bf16* wr = hb + ((size_t)((t + 1) & 1)) * 32768;
#pragma unroll
      for (int g = 0; g < 4; ++g) acc[g] += red[g][L];
      const int col = hs * 16 + lc;

      // compute all 4 rows first (keep hv/cn in regs)
      float hv_[4], cn_[4];
#pragma unroll
      for (int r = 0; r < 4; ++r) {
        float fg = sigm(acc[0][r] + bsv[0]);
        float ig = sigm(acc[1][r] + bsv[1]);
        float og = sigm(acc[2][r] + bsv[2]);
        float gg = tanh_f(acc[3][r] + bsv[3]);
        float cn = fg * cst[r] + ig * gg;
        cst[r] = cn;
        cn_[r] = cn;
        hv_[r] = og * tanh_f(cn);
      }

      // 1) h stores (device-scope write-through) FIRST
#pragma unroll
      for (int r = 0; r < 4; ++r) {
        int orow = mt * 16 + quad * 4 + r;
        unsigned short hbits = __builtin_bit_cast(unsigned short, (__bf16)hv_[r]);
        __hip_atomic_store((unsigned short*)&wr[orow * 512 + col], hbits,
                           __ATOMIC_RELAXED, __HIP_MEMORY_SCOPE_AGENT);
      }
      // 2) drain h stores to the coherence point, then publish flag
      asm volatile("s_waitcnt vmcnt(0)" ::: "memory");
      if (tid == 64)
        __hip_atomic_store(fmine, (unsigned int)(t + 1), __ATOMIC_RELAXED,
                           __HIP_MEMORY_SCOPE_AGENT);
      // 3) HBM output stores AFTER the flag — off the critical path
      float* oseq = out + (size_t)t * 64 * 512;
#pragma unroll
      for (int r = 0; r < 4; ++r) {
        int orow = mt * 16 + quad * 4 + r;
        oseq[orow * 512 + col] = hv_[r];
        if (t == S_LEN - 1) {
          out[16777216 + orow * 512 + col] = hv_[r];               // final h
          out[16777216 + 32768 + orow * 512 + col] = cn_[r];       // final c
        }
      }
    }
    px += 64 * 256;
  }
}

extern "C" void kernel_launch(void* const* d_in, const int* in_sizes, int n_in,
                              void* d_out, int out_size, void* d_ws, size_t ws_size,
                              hipStream_t stream) {
  char* ws = (char*)d_ws;
  __bf16* Wswz = (__bf16*)(ws + OFF_W);
  float*  bias = (float*)(ws + OFF_BIAS);
  __bf16* xb   = (__bf16*)(ws + OFF_X);
  __bf16* hb   = (__bf16*)(ws + OFF_H);
  unsigned int* flg = (unsigned int*)(ws + OFF_FLG);

  // zero h double-buffer + flag words (ws is poisoned 0xAA each call)
  hipMemsetAsync(ws + OFF_H, 0, 131072 + 8192, stream);

  k_conv_x<<<8192, 256, 0, stream>>>((const float*)d_in[0], xb);
  k_conv_w<<<768, 256, 0, stream>>>(
      (const float*)d_in[1],  (const float*)d_in[3],    // f: Wx, Wh
      (const float*)d_in[5],  (const float*)d_in[7],    // i
      (const float*)d_in[9],  (const float*)d_in[11],   // o
      (const float*)d_in[13], (const float*)d_in[15],   // g
      Wswz);
  k_conv_bias<<<8, 256, 0, stream>>>(
      (const float*)d_in[2],  (const float*)d_in[4],
      (const float*)d_in[6],  (const float*)d_in[8],
      (const float*)d_in[10], (const float*)d_in[12],
      (const float*)d_in[14], (const float*)d_in[16],
      bias);
  lstm_seq<<<NBLK, 128, 0, stream>>>(Wswz, bias, xb, hb, flg, (float*)d_out);
}

// Round 8
// 2045.365 us; speedup vs baseline: 1.1932x; 1.0147x over previous
//
#include <hip/hip_runtime.h>

// LSTM S=512 B=64 I=256 H=512, gates order f,i,o,g (4H=2048 cols).
// Persistent-register weights, fused [x_t|h] @ W recurrent GEMM.
// R10 = exact R3 skeleton (proven 1711us: 64B-strided per-producer flags,
// tight spin, drain-then-flag publish) + ONE change:
//   pipelined poll: 4 outstanding flag loads in a ring; check the oldest
//   (vmcnt(3)), shift, reissue. Poll-loop iteration drops from one full
//   agent-load RT (~1600cy) to ~RT/4, cutting average detect delay ~600cy
//   per step. Protocol identical; no new primitives.
// R9 lesson: s_sleep backoff REGRESSED (1975us) -> tight spin's fast
// detection beats lower poll rate; flag-poll congestion theory refuted.
// R6 lesson: bulk tagged-data polling (100x traffic) is the storm to avoid.
// R7/R8 lesson: don't pack cross-XCD flag writers into one line (hang).

#define S_LEN 512
#define NBLK  128
#define GROUP 32

typedef __attribute__((ext_vector_type(8))) __bf16 bf16x8;
typedef __attribute__((ext_vector_type(4))) float  f32x4;

// workspace layout (bytes)
#define OFF_W    ((size_t)0)          // swizzled W: 3,145,728
#define OFF_BIAS ((size_t)3145728)    // 2048 f32
#define OFF_X    ((size_t)4194304)    // x bf16: 16,777,216
#define OFF_H    ((size_t)20971520)   // h double buffer: 2*64*512*2 = 131072
#define OFF_FLG  ((size_t)21102592)   // 4 groups * 32 producers * 64B = 8192

// ---- prelude: x fp32 -> bf16 ----
__global__ void k_conv_x(const float* __restrict__ x, __bf16* __restrict__ xb) {
  int i = blockIdx.x * 256 + threadIdx.x;      // 2,097,152 threads exactly
  float4 v = ((const float4*)x)[i];
  union { __bf16 b[4]; uint2 u; } p;
  p.b[0] = (__bf16)v.x; p.b[1] = (__bf16)v.y;
  p.b[2] = (__bf16)v.z; p.b[3] = (__bf16)v.w;
  ((uint2*)xb)[i] = p.u;
}

// ---- prelude: W -> bf16, MFMA-B-fragment-swizzled ----
// frag tid = ((hs*4+g)*24 + kk)*64 + L ; lane L holds 8 bf16:
// W[k = kk*32 + (L>>4)*8 + j][col = hs*16 + (L&15)] ; k<256 -> Wx else Wh.
__global__ void k_conv_w(const float* __restrict__ wxf, const float* __restrict__ whf,
                         const float* __restrict__ wxi, const float* __restrict__ whi,
                         const float* __restrict__ wxo, const float* __restrict__ who,
                         const float* __restrict__ wxg, const float* __restrict__ whg,
                         __bf16* __restrict__ Wswz) {
  int tid = blockIdx.x * 256 + threadIdx.x;    // 196,608 threads exactly
  int L = tid & 63;
  int q = tid >> 6;
  int kk = q % 24;
  int q2 = q / 24;
  int g  = q2 & 3;
  int hs = q2 >> 2;
  const float* Wx = (g == 0) ? wxf : (g == 1) ? wxi : (g == 2) ? wxo : wxg;
  const float* Wh = (g == 0) ? whf : (g == 1) ? whi : (g == 2) ? who : whg;
  int col = hs * 16 + (L & 15);
  int k0  = kk * 32 + (L >> 4) * 8;
  union { __bf16 b[8]; uint4 u; } p;
#pragma unroll
  for (int j = 0; j < 8; ++j) {
    int k = k0 + j;
    float v = (k < 256) ? Wx[k * 512 + col] : Wh[(k - 256) * 512 + col];
    p.b[j] = (__bf16)v;
  }
  ((uint4*)Wswz)[tid] = p.u;
}

// ---- prelude: combined bias b = bx + bh, layout [gate][512] ----
__global__ void k_conv_bias(const float* __restrict__ bxf, const float* __restrict__ bhf,
                            const float* __restrict__ bxi, const float* __restrict__ bhi,
                            const float* __restrict__ bxo, const float* __restrict__ bho,
                            const float* __restrict__ bxg, const float* __restrict__ bhg,
                            float* __restrict__ bc) {
  int n = blockIdx.x * 256 + threadIdx.x;      // 2048 exactly
  int g = n >> 9, h = n & 511;
  const float* bx = (g == 0) ? bxf : (g == 1) ? bxi : (g == 2) ? bxo : bxg;
  const float* bh = (g == 0) ? bhf : (g == 1) ? bhi : (g == 2) ? bho : bhg;
  bc[n] = bx[h] + bh[h];
}

__device__ __forceinline__ float sigm(float x) { return 1.f / (1.f + __expf(-x)); }
__device__ __forceinline__ float tanh_f(float x) { return 1.f - 2.f / (1.f + __expf(2.f * x)); }

// device-scope (IF-coherent, L2-bypass) 16B h-fragment load as 2x b64 atomics
__device__ __forceinline__ bf16x8 load_h8(const __bf16* p) {
  union { unsigned long long q[2]; bf16x8 v; } u;
  u.q[0] = __hip_atomic_load((const unsigned long long*)p,       __ATOMIC_RELAXED, __HIP_MEMORY_SCOPE_AGENT);
  u.q[1] = __hip_atomic_load((const unsigned long long*)(p + 4), __ATOMIC_RELAXED, __HIP_MEMORY_SCOPE_AGENT);
  return u.v;
}

// ---- main recurrent kernel ----
// block (mt, hs): mt = batch tile (16 rows), hs = hidden slice (16 units).
// wave0: K=[0,384) (x + h[0:128)); wave1: K=[384,768) (h[128:512)).
// Partial sums reduced through LDS; wave1 does gates/c/h + output stores.
// Per-producer flag word (64B lines), value = last completed step + 1.
// Poll: 4-deep pipelined ring of flag loads, oldest-checked-first.
__global__ __launch_bounds__(128, 1) void lstm_seq(
    const __bf16* __restrict__ Wswz, const float* __restrict__ bias,
    const __bf16* __restrict__ xb, __bf16* __restrict__ hb,
    unsigned int* __restrict__ flg, float* __restrict__ out) {
  const int tid  = threadIdx.x;
  const int w    = tid >> 6;
  const int L    = tid & 63;
  const int quad = L >> 4;
  const int lc   = L & 15;
  const int mt   = blockIdx.x & 3;
  const int hs   = blockIdx.x >> 2;

  __shared__ f32x4 red[4][64];

  // persistent weight fragments: 12 K-steps x 4 gates
  bf16x8 Wf[12][4];
  {
    const uint4* wp = (const uint4*)Wswz;
#pragma unroll
    for (int g = 0; g < 4; ++g)
#pragma unroll
      for (int kkl = 0; kkl < 12; ++kkl) {
        int kk = w * 12 + kkl;
        uint4 u = wp[(((size_t)(hs * 4 + g) * 24 + kk) << 6) + L];
        Wf[kkl][g] = __builtin_bit_cast(bf16x8, u);
      }
  }
  float bsv[4];
#pragma unroll
  for (int g = 0; g < 4; ++g) bsv[g] = bias[g * 512 + hs * 16 + lc];

  const int row = mt * 16 + lc;              // A-row this lane loads
  const __bf16* px = xb + (size_t)row * 256 + quad * 8;
  const __bf16* ph0 = hb + (size_t)row * 512 + quad * 8;
  const __bf16* ph1 = ph0 + 32768;

  // poll setup: lane q = L&31 watches flag of producer (mt, q), 64B stride
  const int q = L & 31;
  const unsigned int* fpoll = flg + (((size_t)mt * 32 + q) << 4);
  const bool fdep = (w == 0) ? (q < 8) : (q >= 8);
  unsigned int* fmine = flg + (((size_t)mt * 32 + hs) << 4);

  f32x4 cst = {0.f, 0.f, 0.f, 0.f};          // cell state (wave1 only)

  for (int t = 0; t < S_LEN; ++t) {
    const __bf16* rd = (t & 1) ? ph1 : ph0;
    bf16x8 Af[12];

    // x prefetch under the barrier wait (plain cached loads, wave0 only)
    if (w == 0) {
#pragma unroll
      for (int kkl = 0; kkl < 8; ++kkl)
        Af[kkl] = __builtin_bit_cast(bf16x8, *(const uint4*)(px + kkl * 32));
    }

    // wait for previous step's producers this wave depends on:
    // 4-deep pipelined poll — check oldest in-flight load, reissue.
    if (t > 0) {
      const unsigned int need = (unsigned int)t;
      unsigned int f0 = __hip_atomic_load(fpoll, __ATOMIC_RELAXED, __HIP_MEMORY_SCOPE_AGENT);
      unsigned int f1 = __hip_atomic_load(fpoll, __ATOMIC_RELAXED, __HIP_MEMORY_SCOPE_AGENT);
      unsigned int f2 = __hip_atomic_load(fpoll, __ATOMIC_RELAXED, __HIP_MEMORY_SCOPE_AGENT);
      unsigned int f3 = __hip_atomic_load(fpoll, __ATOMIC_RELAXED, __HIP_MEMORY_SCOPE_AGENT);
      for (;;) {
        if (__ballot(fdep && (f0 < need)) == 0ull) break;
        f0 = f1; f1 = f2; f2 = f3;
        f3 = __hip_atomic_load(fpoll, __ATOMIC_RELAXED, __HIP_MEMORY_SCOPE_AGENT);
      }
    }

    // h fragment loads, device-scope (bypass stale L2, hit IF)
    if (w == 0) {
#pragma unroll
      for (int kkl = 8; kkl < 12; ++kkl)
        Af[kkl] = load_h8(rd + (kkl - 8) * 32);
    } else {
#pragma unroll
      for (int kkl = 0; kkl < 12; ++kkl)
        Af[kkl] = load_h8(rd + 128 + kkl * 32);
    }

    f32x4 acc[4] = {{0,0,0,0},{0,0,0,0},{0,0,0,0},{0,0,0,0}};
#pragma unroll
    for (int kkl = 0; kkl < 12; ++kkl)
#pragma unroll
      for (int g = 0; g < 4; ++g)
        acc[g] = __builtin_amdgcn_mfma_f32_16x16x32_bf16(Af[kkl], Wf[kkl][g], acc[g], 0, 0, 0);

    if (w == 0) {
#pragma unroll
      for (int g = 0; g < 4; ++g) red[g][L] = acc[g];
    }
    __syncthreads();

    if (w == 1) {
      __bf16* wr = hb + ((size_t)((t + 1) & 1)) * 32768;
#pragma unroll
      for (int g = 0; g < 4; ++g) acc[g] += red[g][L];
      const int col = hs * 16 + lc;

      // compute all 4 rows first (keep hv/cn in regs)
      float hv_[4], cn_[4];
#pragma unroll
      for (int r = 0; r < 4; ++r) {
        float fg = sigm(acc[0][r] + bsv[0]);
        float ig = sigm(acc[1][r] + bsv[1]);
        float og = sigm(acc[2][r] + bsv[2]);
        float gg = tanh_f(acc[3][r] + bsv[3]);
        float cn = fg * cst[r] + ig * gg;
        cst[r] = cn;
        cn_[r] = cn;
        hv_[r] = og * tanh_f(cn);
      }

      // 1) h stores (device-scope write-through) FIRST
#pragma unroll
      for (int r = 0; r < 4; ++r) {
        int orow = mt * 16 + quad * 4 + r;
        unsigned short hbits = __builtin_bit_cast(unsigned short, (__bf16)hv_[r]);
        __hip_atomic_store((unsigned short*)&wr[orow * 512 + col], hbits,
                           __ATOMIC_RELAXED, __HIP_MEMORY_SCOPE_AGENT);
      }
      // 2) drain h stores to the coherence point, then publish flag
      asm volatile("s_waitcnt vmcnt(0)" ::: "memory");
      if (tid == 64)
        __hip_atomic_store(fmine, (unsigned int)(t + 1), __ATOMIC_RELAXED,
                           __HIP_MEMORY_SCOPE_AGENT);
      // 3) HBM output stores AFTER the flag — off the critical path
      float* oseq = out + (size_t)t * 64 * 512;
#pragma unroll
      for (int r = 0; r < 4; ++r) {
        int orow = mt * 16 + quad * 4 + r;
        oseq[orow * 512 + col] = hv_[r];
        if (t == S_LEN - 1) {
          out[16777216 + orow * 512 + col] = hv_[r];               // final h
          out[16777216 + 32768 + orow * 512 + col] = cn_[r];       // final c
        }
      }
    }
    px += 64 * 256;
  }
}

extern "C" void kernel_launch(void* const* d_in, const int* in_sizes, int n_in,
                              void* d_out, int out_size, void* d_ws, size_t ws_size,
                              hipStream_t stream) {
  char* ws = (char*)d_ws;
  __bf16* Wswz = (__bf16*)(ws + OFF_W);
  float*  bias = (float*)(ws + OFF_BIAS);
  __bf16* xb   = (__bf16*)(ws + OFF_X);
  __bf16* hb   = (__bf16*)(ws + OFF_H);
  unsigned int* flg = (unsigned int*)(ws + OFF_FLG);

  // zero h double-buffer + flag words (ws is poisoned 0xAA each call)
  hipMemsetAsync(ws + OFF_H, 0, 131072 + 8192, stream);

  k_conv_x<<<8192, 256, 0, stream>>>((const float*)d_in[0], xb);
  k_conv_w<<<768, 256, 0, stream>>>(
      (const float*)d_in[1],  (const float*)d_in[3],    // f: Wx, Wh
      (const float*)d_in[5],  (const float*)d_in[7],    // i
      (const float*)d_in[9],  (const float*)d_in[11],   // o
      (const float*)d_in[13], (const float*)d_in[15],   // g
      Wswz);
  k_conv_bias<<<8, 256, 0, stream>>>(
      (const float*)d_in[2],  (const float*)d_in[4],
      (const float*)d_in[6],  (const float*)d_in[8],
      (const float*)d_in[10], (const float*)d_in[12],
      (const float*)d_in[14], (const float*)d_in[16],
      bias);
  lstm_seq<<<NBLK, 128, 0, stream>>>(Wswz, bias, xb, hb, flg, (float*)d_out);
}